// Round 1
// baseline (1822.771 us; speedup 1.0000x reference)
//
#include <hip/hip_runtime.h>
#include <hip/hip_bf16.h>

#define N_NODES 20000
#define N_EDGES 320000
#define NG 16

// ---------------------------------------------------------------------------
// K0: globals precompute: g2e = globals @ Wg2.T, g2n = globals @ Wng2.T,
//     gg = globals @ Wgg.T + bg.   All [16][128].
__global__ __launch_bounds__(256) void k_glob(
    const float* __restrict__ globals_, const float* __restrict__ Wg2,
    const float* __restrict__ Wng2, const float* __restrict__ Wgg,
    const float* __restrict__ bg, float* __restrict__ g2e,
    float* __restrict__ g2n, float* __restrict__ gg) {
  int idx = blockIdx.x * 256 + threadIdx.x;
  if (idx >= 3 * 2048) return;
  int arr = idx >> 11;
  int rem = idx & 2047;
  int g = rem >> 7, c = rem & 127;
  const float* W = arr == 0 ? Wg2 : (arr == 1 ? Wng2 : Wgg);
  float acc = (arr == 2) ? bg[c] : 0.f;
#pragma unroll
  for (int k = 0; k < 16; ++k) acc += globals_[g * 16 + k] * W[c * 16 + k];
  float* o = arr == 0 ? g2e : (arr == 1 ? g2n : gg);
  o[rem] = acc;
}

// ---------------------------------------------------------------------------
// K1: counts + edge_graph.  idx<E: edge side; else node side.
__global__ __launch_bounds__(256) void k_counts(
    const int* __restrict__ recv, const int* __restrict__ node_graph,
    int* __restrict__ edge_graph, int* __restrict__ cnt_node,
    int* __restrict__ node_cnt_g, int* __restrict__ edge_cnt_g) {
  __shared__ int le[NG], ln[NG];
  int tid = threadIdx.x;
  if (tid < NG) { le[tid] = 0; ln[tid] = 0; }
  __syncthreads();
  int idx = blockIdx.x * 256 + tid;
  if (idx < N_EDGES) {
    int r = recv[idx];
    atomicAdd(&cnt_node[r], 1);
    int g = node_graph[r];
    edge_graph[idx] = g;
    atomicAdd(&le[g], 1);
  } else if (idx < N_EDGES + N_NODES) {
    int n = idx - N_EDGES;
    atomicAdd(&ln[node_graph[n]], 1);
  }
  __syncthreads();
  if (tid < NG && le[tid]) atomicAdd(&edge_cnt_g[tid], le[tid]);
  if (tid >= NG && tid < 2 * NG && ln[tid - NG]) atomicAdd(&node_cnt_g[tid - NG], ln[tid - NG]);
}

// ---------------------------------------------------------------------------
// K2: e1 = relu(edge_feats @ We1.T + be1)  [E,256], store bf16,
//     fused atomic agg1_sum[recv] += e1.
// Tile: 32 edges x 128 cols (blockIdx.y = col half), K=32 single chunk.
__global__ __launch_bounds__(256) void k_e1(
    const float* __restrict__ edge_feats, const float* __restrict__ We1,
    const float* __restrict__ be1, const int* __restrict__ recv,
    __hip_bfloat16* __restrict__ e1, float* __restrict__ agg1) {
  __shared__ float xs[32][36];
  __shared__ float wsh[32][132];
  __shared__ int recv_s[32];
  const int tid = threadIdx.x;
  const int e0 = blockIdx.x * 32;
  const int c0 = blockIdx.y * 128;
  if (tid < 32) recv_s[tid] = recv[e0 + tid];
#pragma unroll
  for (int i = 0; i < 4; ++i) {
    int flat = tid + i * 256;
    int e = flat >> 5, k = flat & 31;
    xs[k][e] = edge_feats[(size_t)(e0 + e) * 32 + k];
  }
#pragma unroll
  for (int i = 0; i < 16; ++i) {
    int flat = tid + i * 256;
    int c = flat >> 5, k = flat & 31;
    wsh[k][c] = We1[(size_t)(c0 + c) * 32 + k];
  }
  __syncthreads();
  const int tc = (tid & 31) * 4;
  const int te = (tid >> 5) * 4;
  float acc[4][4] = {};
#pragma unroll
  for (int k = 0; k < 32; ++k) {
    float4 xv = *(const float4*)&xs[k][te];
    float4 wv = *(const float4*)&wsh[k][tc];
    float xa[4] = {xv.x, xv.y, xv.z, xv.w};
    float wa[4] = {wv.x, wv.y, wv.z, wv.w};
#pragma unroll
    for (int a = 0; a < 4; ++a)
#pragma unroll
      for (int b = 0; b < 4; ++b) acc[a][b] += xa[a] * wa[b];
  }
#pragma unroll
  for (int a = 0; a < 4; ++a) {
    int e = e0 + te + a;
    int r = recv_s[te + a];
#pragma unroll
    for (int b = 0; b < 4; ++b) {
      int c = c0 + tc + b;
      float v = acc[a][b] + be1[c];
      v = v > 0.f ? v : 0.f;
      e1[(size_t)e * 256 + c] = __float2bfloat16(v);
      atomicAdd(&agg1[(size_t)r * 256 + c], v);
    }
  }
}

// ---------------------------------------------------------------------------
// K3: n1 = relu(node_feats @ Wn1.T + (agg1/cnt) @ Win1.T + bn1) [N,256] bf16
// Tile: 32 nodes x 128 cols (blockIdx.y), K = 64+256 = 320 in chunks of 32.
__global__ __launch_bounds__(256) void k_n1(
    const float* __restrict__ node_feats, const float* __restrict__ agg1,
    const int* __restrict__ cnt_node, const float* __restrict__ Wn1,
    const float* __restrict__ Win1, const float* __restrict__ bn1,
    __hip_bfloat16* __restrict__ n1) {
  __shared__ float xs[32][36];
  __shared__ float wsh[32][132];
  __shared__ float invc[32];
  const int tid = threadIdx.x;
  const int n0 = blockIdx.x * 32;
  const int c0 = blockIdx.y * 128;
  if (tid < 32) {
    int c = cnt_node[n0 + tid];
    invc[tid] = 1.0f / (float)(c > 1 ? c : 1);
  }
  const int tc = (tid & 31) * 4;
  const int te = (tid >> 5) * 4;
  float acc[4][4] = {};
  for (int k0 = 0; k0 < 320; k0 += 32) {
    __syncthreads();
#pragma unroll
    for (int i = 0; i < 4; ++i) {
      int flat = tid + i * 256;
      int e = flat >> 5, k = flat & 31;
      float x;
      if (k0 < 64)
        x = node_feats[(size_t)(n0 + e) * 64 + k0 + k];
      else
        x = agg1[(size_t)(n0 + e) * 256 + (k0 - 64) + k] * invc[e];
      xs[k][e] = x;
    }
#pragma unroll
    for (int i = 0; i < 16; ++i) {
      int flat = tid + i * 256;
      int c = flat >> 5, k = flat & 31;
      float w;
      if (k0 < 64)
        w = Wn1[(size_t)(c0 + c) * 64 + k0 + k];
      else
        w = Win1[(size_t)(c0 + c) * 256 + (k0 - 64) + k];
      wsh[k][c] = w;
    }
    __syncthreads();
#pragma unroll
    for (int k = 0; k < 32; ++k) {
      float4 xv = *(const float4*)&xs[k][te];
      float4 wv = *(const float4*)&wsh[k][tc];
      float xa[4] = {xv.x, xv.y, xv.z, xv.w};
      float wa[4] = {wv.x, wv.y, wv.z, wv.w};
#pragma unroll
      for (int a = 0; a < 4; ++a)
#pragma unroll
        for (int b = 0; b < 4; ++b) acc[a][b] += xa[a] * wa[b];
    }
  }
#pragma unroll
  for (int a = 0; a < 4; ++a) {
    int n = n0 + te + a;
#pragma unroll
    for (int b = 0; b < 4; ++b) {
      int c = c0 + tc + b;
      float v = acc[a][b] + bn1[c];
      v = v > 0.f ? v : 0.f;
      n1[(size_t)n * 256 + c] = __float2bfloat16(v);
    }
  }
}

// ---------------------------------------------------------------------------
// K4: e2 = relu(e1 @ We2.T + g2e[edge_graph] + be2) [E,128] — NOT stored;
//     fused atomic agg2_sum[recv] += e2.
// Tile: 32 edges x 128 cols, K=256 in chunks of 32.
__global__ __launch_bounds__(256) void k_e2(
    const __hip_bfloat16* __restrict__ e1, const float* __restrict__ We2,
    const float* __restrict__ be2, const float* __restrict__ g2e,
    const int* __restrict__ recv, const int* __restrict__ edge_graph,
    float* __restrict__ agg2) {
  __shared__ float xs[32][36];
  __shared__ float wsh[32][132];
  __shared__ int recv_s[32], eg_s[32];
  const int tid = threadIdx.x;
  const int e0 = blockIdx.x * 32;
  if (tid < 32) {
    recv_s[tid] = recv[e0 + tid];
    eg_s[tid] = edge_graph[e0 + tid];
  }
  const int tc = (tid & 31) * 4;
  const int te = (tid >> 5) * 4;
  float acc[4][4] = {};
  for (int k0 = 0; k0 < 256; k0 += 32) {
    __syncthreads();
#pragma unroll
    for (int i = 0; i < 4; ++i) {
      int flat = tid + i * 256;
      int e = flat >> 5, k = flat & 31;
      xs[k][e] = __bfloat162float(e1[(size_t)(e0 + e) * 256 + k0 + k]);
    }
#pragma unroll
    for (int i = 0; i < 16; ++i) {
      int flat = tid + i * 256;
      int c = flat >> 5, k = flat & 31;
      wsh[k][c] = We2[(size_t)c * 256 + k0 + k];
    }
    __syncthreads();
#pragma unroll
    for (int k = 0; k < 32; ++k) {
      float4 xv = *(const float4*)&xs[k][te];
      float4 wv = *(const float4*)&wsh[k][tc];
      float xa[4] = {xv.x, xv.y, xv.z, xv.w};
      float wa[4] = {wv.x, wv.y, wv.z, wv.w};
#pragma unroll
      for (int a = 0; a < 4; ++a)
#pragma unroll
        for (int b = 0; b < 4; ++b) acc[a][b] += xa[a] * wa[b];
    }
  }
#pragma unroll
  for (int a = 0; a < 4; ++a) {
    int r = recv_s[te + a];
    int g = eg_s[te + a];
#pragma unroll
    for (int b = 0; b < 4; ++b) {
      int c = tc + b;
      float v = acc[a][b] + be2[c] + g2e[g * 128 + c];
      v = v > 0.f ? v : 0.f;
      atomicAdd(&agg2[(size_t)r * 128 + c], v);
    }
  }
}

// ---------------------------------------------------------------------------
// K5: n2 = relu(n1 @ Wn2.T + (agg2/cnt) @ Win2.T + g2n[node_graph] + bn2)
//     [N,128] bf16.  Tile: 32 nodes x 128 cols, K = 256+128 = 384.
__global__ __launch_bounds__(256) void k_n2(
    const __hip_bfloat16* __restrict__ n1, const float* __restrict__ agg2,
    const int* __restrict__ cnt_node, const float* __restrict__ Wn2,
    const float* __restrict__ Win2, const float* __restrict__ bn2,
    const float* __restrict__ g2n, const int* __restrict__ node_graph,
    __hip_bfloat16* __restrict__ n2) {
  __shared__ float xs[32][36];
  __shared__ float wsh[32][132];
  __shared__ float invc[32];
  __shared__ int ng_s[32];
  const int tid = threadIdx.x;
  const int n0 = blockIdx.x * 32;
  if (tid < 32) {
    int c = cnt_node[n0 + tid];
    invc[tid] = 1.0f / (float)(c > 1 ? c : 1);
    ng_s[tid] = node_graph[n0 + tid];
  }
  const int tc = (tid & 31) * 4;
  const int te = (tid >> 5) * 4;
  float acc[4][4] = {};
  for (int k0 = 0; k0 < 384; k0 += 32) {
    __syncthreads();
#pragma unroll
    for (int i = 0; i < 4; ++i) {
      int flat = tid + i * 256;
      int e = flat >> 5, k = flat & 31;
      float x;
      if (k0 < 256)
        x = __bfloat162float(n1[(size_t)(n0 + e) * 256 + k0 + k]);
      else
        x = agg2[(size_t)(n0 + e) * 128 + (k0 - 256) + k] * invc[e];
      xs[k][e] = x;
    }
#pragma unroll
    for (int i = 0; i < 16; ++i) {
      int flat = tid + i * 256;
      int c = flat >> 5, k = flat & 31;
      float w;
      if (k0 < 256)
        w = Wn2[(size_t)c * 256 + k0 + k];
      else
        w = Win2[(size_t)c * 128 + (k0 - 256) + k];
      wsh[k][c] = w;
    }
    __syncthreads();
#pragma unroll
    for (int k = 0; k < 32; ++k) {
      float4 xv = *(const float4*)&xs[k][te];
      float4 wv = *(const float4*)&wsh[k][tc];
      float xa[4] = {xv.x, xv.y, xv.z, xv.w};
      float wa[4] = {wv.x, wv.y, wv.z, wv.w};
#pragma unroll
      for (int a = 0; a < 4; ++a)
#pragma unroll
        for (int b = 0; b < 4; ++b) acc[a][b] += xa[a] * wa[b];
    }
  }
#pragma unroll
  for (int a = 0; a < 4; ++a) {
    int n = n0 + te + a;
    int g = ng_s[te + a];
#pragma unroll
    for (int b = 0; b < 4; ++b) {
      int c = tc + b;
      float v = acc[a][b] + bn2[c] + g2n[g * 128 + c];
      v = v > 0.f ? v : 0.f;
      n2[(size_t)n * 128 + c] = __float2bfloat16(v);
    }
  }
}

// ---------------------------------------------------------------------------
// K6: per-graph sums of n2 (-> node_sum) and agg2_sum (-> edge_sum, since
//     sum_e[e in g] e2 == sum_n[n in g] agg2_sum[n]).  node_graph is sorted,
//     so accumulate runs in registers and flush on graph change.
__global__ __launch_bounds__(128) void k_gsum(
    const __hip_bfloat16* __restrict__ n2, const float* __restrict__ agg2,
    const int* __restrict__ node_graph, float* __restrict__ node_sum,
    float* __restrict__ edge_sum) {
  const int c = threadIdx.x;
  const int n0 = blockIdx.x * 100;
  float na = 0.f, ea = 0.f;
  int gcur = node_graph[n0];
  for (int j = 0; j < 100; ++j) {
    int n = n0 + j;
    int g = node_graph[n];
    if (g != gcur) {
      atomicAdd(&node_sum[gcur * 128 + c], na);
      atomicAdd(&edge_sum[gcur * 128 + c], ea);
      na = 0.f;
      ea = 0.f;
      gcur = g;
    }
    na += __bfloat162float(n2[(size_t)n * 128 + c]);
    ea += agg2[(size_t)n * 128 + c];
  }
  atomicAdd(&node_sum[gcur * 128 + c], na);
  atomicAdd(&edge_sum[gcur * 128 + c], ea);
}

// ---------------------------------------------------------------------------
// K7: out = node_avg @ Wgn.T + edge_avg @ Wge.T + gg   [16,128]
__global__ __launch_bounds__(128) void k_final(
    const float* __restrict__ node_sum, const float* __restrict__ edge_sum,
    const int* __restrict__ node_cnt_g, const int* __restrict__ edge_cnt_g,
    const float* __restrict__ Wgn, const float* __restrict__ Wge,
    const float* __restrict__ gg, float* __restrict__ out) {
  __shared__ float navg[128], eavg[128];
  const int g = blockIdx.x, c = threadIdx.x;
  int nc = node_cnt_g[g];
  nc = nc > 1 ? nc : 1;
  int ec = edge_cnt_g[g];
  ec = ec > 1 ? ec : 1;
  navg[c] = node_sum[g * 128 + c] / (float)nc;
  eavg[c] = edge_sum[g * 128 + c] / (float)ec;
  __syncthreads();
  float acc = gg[g * 128 + c];
#pragma unroll 4
  for (int k = 0; k < 128; ++k)
    acc += navg[k] * Wgn[c * 128 + k] + eavg[k] * Wge[c * 128 + k];
  out[g * 128 + c] = acc;
}

// ---------------------------------------------------------------------------
extern "C" void kernel_launch(void* const* d_in, const int* in_sizes, int n_in,
                              void* d_out, int out_size, void* d_ws, size_t ws_size,
                              hipStream_t stream) {
  const float* node_feats = (const float*)d_in[0];
  const float* edge_feats = (const float*)d_in[1];
  const float* globals_ = (const float*)d_in[2];
  const float* We1 = (const float*)d_in[3];
  const float* be1 = (const float*)d_in[4];
  const float* Wn1 = (const float*)d_in[5];
  const float* Win1 = (const float*)d_in[6];
  const float* bn1 = (const float*)d_in[7];
  const float* We2 = (const float*)d_in[8];
  const float* Wg2 = (const float*)d_in[9];
  const float* be2 = (const float*)d_in[10];
  const float* Wn2 = (const float*)d_in[11];
  const float* Win2 = (const float*)d_in[12];
  const float* Wng2 = (const float*)d_in[13];
  const float* bn2 = (const float*)d_in[14];
  const float* Wgn = (const float*)d_in[15];
  const float* Wge = (const float*)d_in[16];
  const float* Wgg = (const float*)d_in[17];
  const float* bg = (const float*)d_in[18];
  const int* receivers = (const int*)d_in[19];
  const int* node_graph = (const int*)d_in[20];
  float* out = (float*)d_out;

  char* ws = (char*)d_ws;
  size_t off = 0;
  auto alloc = [&](size_t bytes) {
    size_t o = off;
    off += (bytes + 255) & ~(size_t)255;
    return o;
  };
  // --- zeroed region (accumulators) ---
  float* agg1 = (float*)(ws + alloc((size_t)N_NODES * 256 * 4));
  float* agg2 = (float*)(ws + alloc((size_t)N_NODES * 128 * 4));
  int* cnt_node = (int*)(ws + alloc((size_t)N_NODES * 4));
  int* node_cnt_g = (int*)(ws + alloc(NG * 4));
  int* edge_cnt_g = (int*)(ws + alloc(NG * 4));
  float* node_sum = (float*)(ws + alloc(NG * 128 * 4));
  float* edge_sum = (float*)(ws + alloc(NG * 128 * 4));
  size_t zero_bytes = off;
  // --- fully-overwritten region ---
  float* g2e = (float*)(ws + alloc(NG * 128 * 4));
  float* g2n = (float*)(ws + alloc(NG * 128 * 4));
  float* gg = (float*)(ws + alloc(NG * 128 * 4));
  int* edge_graph = (int*)(ws + alloc((size_t)N_EDGES * 4));
  __hip_bfloat16* e1 = (__hip_bfloat16*)(ws + alloc((size_t)N_EDGES * 256 * 2));
  __hip_bfloat16* n1 = (__hip_bfloat16*)(ws + alloc((size_t)N_NODES * 256 * 2));
  __hip_bfloat16* n2 = (__hip_bfloat16*)(ws + alloc((size_t)N_NODES * 128 * 2));
  (void)ws_size;

  hipMemsetAsync(d_ws, 0, zero_bytes, stream);
  k_glob<<<24, 256, 0, stream>>>(globals_, Wg2, Wng2, Wgg, bg, g2e, g2n, gg);
  k_counts<<<(N_EDGES + N_NODES + 255) / 256, 256, 0, stream>>>(
      receivers, node_graph, edge_graph, cnt_node, node_cnt_g, edge_cnt_g);
  k_e1<<<dim3(N_EDGES / 32, 2), 256, 0, stream>>>(edge_feats, We1, be1,
                                                  receivers, e1, agg1);
  k_n1<<<dim3(N_NODES / 32, 2), 256, 0, stream>>>(node_feats, agg1, cnt_node,
                                                  Wn1, Win1, bn1, n1);
  k_e2<<<N_EDGES / 32, 256, 0, stream>>>(e1, We2, be2, g2e, receivers,
                                         edge_graph, agg2);
  k_n2<<<N_NODES / 32, 256, 0, stream>>>(n1, agg2, cnt_node, Wn2, Win2, bn2,
                                         g2n, node_graph, n2);
  k_gsum<<<N_NODES / 100, 128, 0, stream>>>(n2, agg2, node_graph, node_sum,
                                            edge_sum);
  k_final<<<NG, 128, 0, stream>>>(node_sum, edge_sum, node_cnt_g, edge_cnt_g,
                                  Wgn, Wge, gg, out);
}

// Round 2
// 773.534 us; speedup vs baseline: 2.3564x; 2.3564x over previous
//
#include <hip/hip_runtime.h>
#include <hip/hip_bf16.h>

#define N_NODES 20000
#define N_EDGES 320000
#define NG 16

// ---------------------------------------------------------------------------
// K0: globals precompute: g2e = globals @ Wg2.T, g2n = globals @ Wng2.T,
//     gg = globals @ Wgg.T + bg.   All [16][128].
__global__ __launch_bounds__(256) void k_glob(
    const float* __restrict__ globals_, const float* __restrict__ Wg2,
    const float* __restrict__ Wng2, const float* __restrict__ Wgg,
    const float* __restrict__ bg, float* __restrict__ g2e,
    float* __restrict__ g2n, float* __restrict__ gg) {
  int idx = blockIdx.x * 256 + threadIdx.x;
  if (idx >= 3 * 2048) return;
  int arr = idx >> 11;
  int rem = idx & 2047;
  int g = rem >> 7, c = rem & 127;
  const float* W = arr == 0 ? Wg2 : (arr == 1 ? Wng2 : Wgg);
  float acc = (arr == 2) ? bg[c] : 0.f;
#pragma unroll
  for (int k = 0; k < 16; ++k) acc += globals_[g * 16 + k] * W[c * 16 + k];
  float* o = arr == 0 ? g2e : (arr == 1 ? g2n : gg);
  o[rem] = acc;
}

// ---------------------------------------------------------------------------
// K1: counts. idx<E: per-node in-degree + per-graph edge count; else node side.
__global__ __launch_bounds__(256) void k_counts(
    const int* __restrict__ recv, const int* __restrict__ node_graph,
    int* __restrict__ cnt_node, int* __restrict__ node_cnt_g,
    int* __restrict__ edge_cnt_g) {
  __shared__ int le[NG], ln[NG];
  int tid = threadIdx.x;
  if (tid < NG) { le[tid] = 0; ln[tid] = 0; }
  __syncthreads();
  int idx = blockIdx.x * 256 + tid;
  if (idx < N_EDGES) {
    int r = recv[idx];
    atomicAdd(&cnt_node[r], 1);
    atomicAdd(&le[node_graph[r]], 1);
  } else if (idx < N_EDGES + N_NODES) {
    int n = idx - N_EDGES;
    atomicAdd(&ln[node_graph[n]], 1);
  }
  __syncthreads();
  if (tid < NG && le[tid]) atomicAdd(&edge_cnt_g[tid], le[tid]);
  if (tid >= NG && tid < 2 * NG && ln[tid - NG]) atomicAdd(&node_cnt_g[tid - NG], ln[tid - NG]);
}

// ---------------------------------------------------------------------------
// K1b: exclusive prefix sum of cnt_node -> offset[N+1]; zero cursor.
// Single block, chunked Hillis-Steele. ~20000 elements, a few µs.
__global__ __launch_bounds__(256) void k_scan(const int* __restrict__ cnt,
                                              int* __restrict__ offset,
                                              int* __restrict__ cursor) {
  __shared__ int buf[256];
  __shared__ int carry;
  int tid = threadIdx.x;
  if (tid == 0) carry = 0;
  __syncthreads();
  for (int base = 0; base < N_NODES; base += 256) {
    int i = base + tid;
    int v = (i < N_NODES) ? cnt[i] : 0;
    buf[tid] = v;
    __syncthreads();
#pragma unroll
    for (int d = 1; d < 256; d <<= 1) {
      int t = (tid >= d) ? buf[tid - d] : 0;
      __syncthreads();
      buf[tid] += t;
      __syncthreads();
    }
    if (i < N_NODES) {
      offset[i] = carry + buf[tid] - v;
      cursor[i] = 0;
    }
    __syncthreads();
    if (tid == 255) carry += buf[255];
    __syncthreads();
  }
  if (tid == 0) offset[N_NODES] = carry;
}

// ---------------------------------------------------------------------------
// K1c: scatter edges into CSR buckets (receiver-sorted positions).
__global__ __launch_bounds__(256) void k_scatter(
    const int* __restrict__ recv, const int* __restrict__ offset,
    int* __restrict__ cursor, int* __restrict__ pos2edge,
    int* __restrict__ pos2node) {
  int e = blockIdx.x * 256 + threadIdx.x;
  if (e >= N_EDGES) return;
  int n = recv[e];
  int slot = atomicAdd(&cursor[n], 1);
  int pos = offset[n] + slot;
  pos2edge[pos] = e;
  pos2node[pos] = n;
}

// ---------------------------------------------------------------------------
// K2: e1 rows in CSR order: e1s[p] = relu(edge_feats[pos2edge[p]] @ We1.T + be1)
// Tile: 32 positions x 128 cols (blockIdx.y), K=32. No atomics.
__global__ __launch_bounds__(256) void k_e1(
    const float* __restrict__ edge_feats, const float* __restrict__ We1,
    const float* __restrict__ be1, const int* __restrict__ pos2edge,
    __hip_bfloat16* __restrict__ e1s) {
  __shared__ float xs[32][36];
  __shared__ float wsh[32][132];
  __shared__ int pe[32];
  const int tid = threadIdx.x;
  const int p0 = blockIdx.x * 32;
  const int c0 = blockIdx.y * 128;
  if (tid < 32) pe[tid] = pos2edge[p0 + tid];
  __syncthreads();
#pragma unroll
  for (int i = 0; i < 4; ++i) {
    int flat = tid + i * 256;
    int e = flat >> 5, k = flat & 31;
    xs[k][e] = edge_feats[(size_t)pe[e] * 32 + k];
  }
#pragma unroll
  for (int i = 0; i < 16; ++i) {
    int flat = tid + i * 256;
    int c = flat >> 5, k = flat & 31;
    wsh[k][c] = We1[(size_t)(c0 + c) * 32 + k];
  }
  __syncthreads();
  const int tc = (tid & 31) * 4;
  const int te = (tid >> 5) * 4;
  float acc[4][4] = {};
#pragma unroll
  for (int k = 0; k < 32; ++k) {
    float4 xv = *(const float4*)&xs[k][te];
    float4 wv = *(const float4*)&wsh[k][tc];
    float xa[4] = {xv.x, xv.y, xv.z, xv.w};
    float wa[4] = {wv.x, wv.y, wv.z, wv.w};
#pragma unroll
    for (int a = 0; a < 4; ++a)
#pragma unroll
      for (int b = 0; b < 4; ++b) acc[a][b] += xa[a] * wa[b];
  }
#pragma unroll
  for (int a = 0; a < 4; ++a) {
    size_t row = (size_t)(p0 + te + a) * 256;
#pragma unroll
    for (int b = 0; b < 4; ++b) {
      int c = c0 + tc + b;
      float v = acc[a][b] + be1[c];
      v = v > 0.f ? v : 0.f;
      e1s[row + c] = __float2bfloat16(v);
    }
  }
}

// ---------------------------------------------------------------------------
// K2b: agg1[n] = sum of e1s rows offset[n]..offset[n+1] (contiguous). No atomics.
__global__ __launch_bounds__(256) void k_agg1(
    const __hip_bfloat16* __restrict__ e1s, const int* __restrict__ offset,
    float* __restrict__ agg1) {
  int n = blockIdx.x, c = threadIdx.x;
  int s = offset[n], t = offset[n + 1];
  float acc = 0.f;
  for (int p = s; p < t; ++p) acc += __bfloat162float(e1s[(size_t)p * 256 + c]);
  agg1[(size_t)n * 256 + c] = acc;
}

// ---------------------------------------------------------------------------
// K3: n1 = relu(node_feats @ Wn1.T + (agg1/cnt) @ Win1.T + bn1) [N,256] bf16
__global__ __launch_bounds__(256) void k_n1(
    const float* __restrict__ node_feats, const float* __restrict__ agg1,
    const int* __restrict__ cnt_node, const float* __restrict__ Wn1,
    const float* __restrict__ Win1, const float* __restrict__ bn1,
    __hip_bfloat16* __restrict__ n1) {
  __shared__ float xs[32][36];
  __shared__ float wsh[32][132];
  __shared__ float invc[32];
  const int tid = threadIdx.x;
  const int n0 = blockIdx.x * 32;
  const int c0 = blockIdx.y * 128;
  if (tid < 32) {
    int c = cnt_node[n0 + tid];
    invc[tid] = 1.0f / (float)(c > 1 ? c : 1);
  }
  const int tc = (tid & 31) * 4;
  const int te = (tid >> 5) * 4;
  float acc[4][4] = {};
  for (int k0 = 0; k0 < 320; k0 += 32) {
    __syncthreads();
#pragma unroll
    for (int i = 0; i < 4; ++i) {
      int flat = tid + i * 256;
      int e = flat >> 5, k = flat & 31;
      float x;
      if (k0 < 64)
        x = node_feats[(size_t)(n0 + e) * 64 + k0 + k];
      else
        x = agg1[(size_t)(n0 + e) * 256 + (k0 - 64) + k] * invc[e];
      xs[k][e] = x;
    }
#pragma unroll
    for (int i = 0; i < 16; ++i) {
      int flat = tid + i * 256;
      int c = flat >> 5, k = flat & 31;
      float w;
      if (k0 < 64)
        w = Wn1[(size_t)(c0 + c) * 64 + k0 + k];
      else
        w = Win1[(size_t)(c0 + c) * 256 + (k0 - 64) + k];
      wsh[k][c] = w;
    }
    __syncthreads();
#pragma unroll
    for (int k = 0; k < 32; ++k) {
      float4 xv = *(const float4*)&xs[k][te];
      float4 wv = *(const float4*)&wsh[k][tc];
      float xa[4] = {xv.x, xv.y, xv.z, xv.w};
      float wa[4] = {wv.x, wv.y, wv.z, wv.w};
#pragma unroll
      for (int a = 0; a < 4; ++a)
#pragma unroll
        for (int b = 0; b < 4; ++b) acc[a][b] += xa[a] * wa[b];
    }
  }
#pragma unroll
  for (int a = 0; a < 4; ++a) {
    size_t row = (size_t)(n0 + te + a) * 256;
#pragma unroll
    for (int b = 0; b < 4; ++b) {
      int c = c0 + tc + b;
      float v = acc[a][b] + bn1[c];
      v = v > 0.f ? v : 0.f;
      n1[row + c] = __float2bfloat16(v);
    }
  }
}

// ---------------------------------------------------------------------------
// K4: e2 rows in CSR order, written IN PLACE into cols [0,128) of each e1s row
//     (this block's rows are fully read before the epilogue writes them;
//      no other block touches them).  e2 = relu(e1 @ We2.T + g2e[g] + be2).
__global__ __launch_bounds__(256) void k_e2(
    __hip_bfloat16* __restrict__ e1s, const float* __restrict__ We2,
    const float* __restrict__ be2, const float* __restrict__ g2e,
    const int* __restrict__ pos2node, const int* __restrict__ node_graph) {
  __shared__ float xs[32][36];
  __shared__ float wsh[32][132];
  __shared__ int gid[32];
  const int tid = threadIdx.x;
  const int p0 = blockIdx.x * 32;
  if (tid < 32) gid[tid] = node_graph[pos2node[p0 + tid]];
  const int tc = (tid & 31) * 4;
  const int te = (tid >> 5) * 4;
  float acc[4][4] = {};
  for (int k0 = 0; k0 < 256; k0 += 32) {
    __syncthreads();
#pragma unroll
    for (int i = 0; i < 4; ++i) {
      int flat = tid + i * 256;
      int e = flat >> 5, k = flat & 31;
      xs[k][e] = __bfloat162float(e1s[(size_t)(p0 + e) * 256 + k0 + k]);
    }
#pragma unroll
    for (int i = 0; i < 16; ++i) {
      int flat = tid + i * 256;
      int c = flat >> 5, k = flat & 31;
      wsh[k][c] = We2[(size_t)c * 256 + k0 + k];
    }
    __syncthreads();
#pragma unroll
    for (int k = 0; k < 32; ++k) {
      float4 xv = *(const float4*)&xs[k][te];
      float4 wv = *(const float4*)&wsh[k][tc];
      float xa[4] = {xv.x, xv.y, xv.z, xv.w};
      float wa[4] = {wv.x, wv.y, wv.z, wv.w};
#pragma unroll
      for (int a = 0; a < 4; ++a)
#pragma unroll
        for (int b = 0; b < 4; ++b) acc[a][b] += xa[a] * wa[b];
    }
  }
#pragma unroll
  for (int a = 0; a < 4; ++a) {
    size_t row = (size_t)(p0 + te + a) * 256;
    int g = gid[te + a];
#pragma unroll
    for (int b = 0; b < 4; ++b) {
      int c = tc + b;
      float v = acc[a][b] + be2[c] + g2e[g * 128 + c];
      v = v > 0.f ? v : 0.f;
      e1s[row + c] = __float2bfloat16(v);
    }
  }
}

// ---------------------------------------------------------------------------
// K4b: agg2[n] = sum of e2 rows (stored at e1s row stride, cols 0..127).
__global__ __launch_bounds__(128) void k_agg2(
    const __hip_bfloat16* __restrict__ e2s, const int* __restrict__ offset,
    float* __restrict__ agg2) {
  int n = blockIdx.x, c = threadIdx.x;
  int s = offset[n], t = offset[n + 1];
  float acc = 0.f;
  for (int p = s; p < t; ++p) acc += __bfloat162float(e2s[(size_t)p * 256 + c]);
  agg2[(size_t)n * 128 + c] = acc;
}

// ---------------------------------------------------------------------------
// K5: n2 = relu(n1 @ Wn2.T + (agg2/cnt) @ Win2.T + g2n[node_graph] + bn2)
__global__ __launch_bounds__(256) void k_n2(
    const __hip_bfloat16* __restrict__ n1, const float* __restrict__ agg2,
    const int* __restrict__ cnt_node, const float* __restrict__ Wn2,
    const float* __restrict__ Win2, const float* __restrict__ bn2,
    const float* __restrict__ g2n, const int* __restrict__ node_graph,
    __hip_bfloat16* __restrict__ n2) {
  __shared__ float xs[32][36];
  __shared__ float wsh[32][132];
  __shared__ float invc[32];
  __shared__ int ng_s[32];
  const int tid = threadIdx.x;
  const int n0 = blockIdx.x * 32;
  if (tid < 32) {
    int c = cnt_node[n0 + tid];
    invc[tid] = 1.0f / (float)(c > 1 ? c : 1);
    ng_s[tid] = node_graph[n0 + tid];
  }
  const int tc = (tid & 31) * 4;
  const int te = (tid >> 5) * 4;
  float acc[4][4] = {};
  for (int k0 = 0; k0 < 384; k0 += 32) {
    __syncthreads();
#pragma unroll
    for (int i = 0; i < 4; ++i) {
      int flat = tid + i * 256;
      int e = flat >> 5, k = flat & 31;
      float x;
      if (k0 < 256)
        x = __bfloat162float(n1[(size_t)(n0 + e) * 256 + k0 + k]);
      else
        x = agg2[(size_t)(n0 + e) * 128 + (k0 - 256) + k] * invc[e];
      xs[k][e] = x;
    }
#pragma unroll
    for (int i = 0; i < 16; ++i) {
      int flat = tid + i * 256;
      int c = flat >> 5, k = flat & 31;
      float w;
      if (k0 < 256)
        w = Wn2[(size_t)c * 256 + k0 + k];
      else
        w = Win2[(size_t)c * 128 + (k0 - 256) + k];
      wsh[k][c] = w;
    }
    __syncthreads();
#pragma unroll
    for (int k = 0; k < 32; ++k) {
      float4 xv = *(const float4*)&xs[k][te];
      float4 wv = *(const float4*)&wsh[k][tc];
      float xa[4] = {xv.x, xv.y, xv.z, xv.w};
      float wa[4] = {wv.x, wv.y, wv.z, wv.w};
#pragma unroll
      for (int a = 0; a < 4; ++a)
#pragma unroll
        for (int b = 0; b < 4; ++b) acc[a][b] += xa[a] * wa[b];
    }
  }
#pragma unroll
  for (int a = 0; a < 4; ++a) {
    int n = n0 + te + a;
    int g = ng_s[te + a];
#pragma unroll
    for (int b = 0; b < 4; ++b) {
      int c = tc + b;
      float v = acc[a][b] + bn2[c] + g2n[g * 128 + c];
      v = v > 0.f ? v : 0.f;
      n2[(size_t)n * 128 + c] = __float2bfloat16(v);
    }
  }
}

// ---------------------------------------------------------------------------
// K6: per-graph sums of n2 and agg2 (edge_sum[g] = sum_{n in g} agg2[n]).
//     node_graph sorted -> register runs, flush on change.
__global__ __launch_bounds__(128) void k_gsum(
    const __hip_bfloat16* __restrict__ n2, const float* __restrict__ agg2,
    const int* __restrict__ node_graph, float* __restrict__ node_sum,
    float* __restrict__ edge_sum) {
  const int c = threadIdx.x;
  const int n0 = blockIdx.x * 100;
  float na = 0.f, ea = 0.f;
  int gcur = node_graph[n0];
  for (int j = 0; j < 100; ++j) {
    int n = n0 + j;
    int g = node_graph[n];
    if (g != gcur) {
      atomicAdd(&node_sum[gcur * 128 + c], na);
      atomicAdd(&edge_sum[gcur * 128 + c], ea);
      na = 0.f;
      ea = 0.f;
      gcur = g;
    }
    na += __bfloat162float(n2[(size_t)n * 128 + c]);
    ea += agg2[(size_t)n * 128 + c];
  }
  atomicAdd(&node_sum[gcur * 128 + c], na);
  atomicAdd(&edge_sum[gcur * 128 + c], ea);
}

// ---------------------------------------------------------------------------
// K7: out = node_avg @ Wgn.T + edge_avg @ Wge.T + gg   [16,128]
__global__ __launch_bounds__(128) void k_final(
    const float* __restrict__ node_sum, const float* __restrict__ edge_sum,
    const int* __restrict__ node_cnt_g, const int* __restrict__ edge_cnt_g,
    const float* __restrict__ Wgn, const float* __restrict__ Wge,
    const float* __restrict__ gg, float* __restrict__ out) {
  __shared__ float navg[128], eavg[128];
  const int g = blockIdx.x, c = threadIdx.x;
  int nc = node_cnt_g[g];
  nc = nc > 1 ? nc : 1;
  int ec = edge_cnt_g[g];
  ec = ec > 1 ? ec : 1;
  navg[c] = node_sum[g * 128 + c] / (float)nc;
  eavg[c] = edge_sum[g * 128 + c] / (float)ec;
  __syncthreads();
  float acc = gg[g * 128 + c];
#pragma unroll 4
  for (int k = 0; k < 128; ++k)
    acc += navg[k] * Wgn[c * 128 + k] + eavg[k] * Wge[c * 128 + k];
  out[g * 128 + c] = acc;
}

// ---------------------------------------------------------------------------
extern "C" void kernel_launch(void* const* d_in, const int* in_sizes, int n_in,
                              void* d_out, int out_size, void* d_ws, size_t ws_size,
                              hipStream_t stream) {
  const float* node_feats = (const float*)d_in[0];
  const float* edge_feats = (const float*)d_in[1];
  const float* globals_ = (const float*)d_in[2];
  const float* We1 = (const float*)d_in[3];
  const float* be1 = (const float*)d_in[4];
  const float* Wn1 = (const float*)d_in[5];
  const float* Win1 = (const float*)d_in[6];
  const float* bn1 = (const float*)d_in[7];
  const float* We2 = (const float*)d_in[8];
  const float* Wg2 = (const float*)d_in[9];
  const float* be2 = (const float*)d_in[10];
  const float* Wn2 = (const float*)d_in[11];
  const float* Win2 = (const float*)d_in[12];
  const float* Wng2 = (const float*)d_in[13];
  const float* bn2 = (const float*)d_in[14];
  const float* Wgn = (const float*)d_in[15];
  const float* Wge = (const float*)d_in[16];
  const float* Wgg = (const float*)d_in[17];
  const float* bg = (const float*)d_in[18];
  const int* receivers = (const int*)d_in[19];
  const int* node_graph = (const int*)d_in[20];
  float* out = (float*)d_out;

  char* ws = (char*)d_ws;
  size_t off = 0;
  auto alloc = [&](size_t bytes) {
    size_t o = off;
    off += (bytes + 255) & ~(size_t)255;
    return o;
  };
  // --- zeroed region (small) ---
  int* cnt_node = (int*)(ws + alloc((size_t)N_NODES * 4));
  int* node_cnt_g = (int*)(ws + alloc(NG * 4));
  int* edge_cnt_g = (int*)(ws + alloc(NG * 4));
  float* node_sum = (float*)(ws + alloc(NG * 128 * 4));
  float* edge_sum = (float*)(ws + alloc(NG * 128 * 4));
  size_t zero_bytes = off;
  // --- fully-overwritten region ---
  int* offset = (int*)(ws + alloc((size_t)(N_NODES + 1) * 4));
  int* cursor = (int*)(ws + alloc((size_t)N_NODES * 4));
  int* pos2edge = (int*)(ws + alloc((size_t)N_EDGES * 4));
  int* pos2node = (int*)(ws + alloc((size_t)N_EDGES * 4));
  float* agg1 = (float*)(ws + alloc((size_t)N_NODES * 256 * 4));
  float* agg2 = (float*)(ws + alloc((size_t)N_NODES * 128 * 4));
  float* g2e = (float*)(ws + alloc(NG * 128 * 4));
  float* g2n = (float*)(ws + alloc(NG * 128 * 4));
  float* gg = (float*)(ws + alloc(NG * 128 * 4));
  __hip_bfloat16* e1s = (__hip_bfloat16*)(ws + alloc((size_t)N_EDGES * 256 * 2));
  __hip_bfloat16* n1 = (__hip_bfloat16*)(ws + alloc((size_t)N_NODES * 256 * 2));
  __hip_bfloat16* n2 = (__hip_bfloat16*)(ws + alloc((size_t)N_NODES * 128 * 2));
  (void)ws_size;

  hipMemsetAsync(d_ws, 0, zero_bytes, stream);
  k_glob<<<24, 256, 0, stream>>>(globals_, Wg2, Wng2, Wgg, bg, g2e, g2n, gg);
  k_counts<<<(N_EDGES + N_NODES + 255) / 256, 256, 0, stream>>>(
      receivers, node_graph, cnt_node, node_cnt_g, edge_cnt_g);
  k_scan<<<1, 256, 0, stream>>>(cnt_node, offset, cursor);
  k_scatter<<<(N_EDGES + 255) / 256, 256, 0, stream>>>(receivers, offset,
                                                       cursor, pos2edge,
                                                       pos2node);
  k_e1<<<dim3(N_EDGES / 32, 2), 256, 0, stream>>>(edge_feats, We1, be1,
                                                  pos2edge, e1s);
  k_agg1<<<N_NODES, 256, 0, stream>>>(e1s, offset, agg1);
  k_n1<<<dim3(N_NODES / 32, 2), 256, 0, stream>>>(node_feats, agg1, cnt_node,
                                                  Wn1, Win1, bn1, n1);
  k_e2<<<N_EDGES / 32, 256, 0, stream>>>(e1s, We2, be2, g2e, pos2node,
                                         node_graph);
  k_agg2<<<N_NODES, 128, 0, stream>>>(e1s, offset, agg2);
  k_n2<<<N_NODES / 32, 256, 0, stream>>>(n1, agg2, cnt_node, Wn2, Win2, bn2,
                                         g2n, node_graph, n2);
  k_gsum<<<N_NODES / 100, 128, 0, stream>>>(n2, agg2, node_graph, node_sum,
                                            edge_sum);
  k_final<<<NG, 128, 0, stream>>>(node_sum, edge_sum, node_cnt_g, edge_cnt_g,
                                  Wgn, Wge, gg, out);
}

// Round 3
// 344.535 us; speedup vs baseline: 5.2905x; 2.2452x over previous
//
#include <hip/hip_runtime.h>
#include <hip/hip_bf16.h>

#define N_NODES 20000
#define N_EDGES 320000
#define NG 16

using bf16 = __hip_bfloat16;
typedef __attribute__((ext_vector_type(8))) short short8v;
typedef __attribute__((ext_vector_type(4))) short short4v;
typedef __attribute__((ext_vector_type(4))) float f32x4;

static __device__ __forceinline__ short f2bs(float f) {
  bf16 h = __float2bfloat16(f);
  union { bf16 b; short s; } u;
  u.b = h;
  return u.s;
}

// ---------------------------------------------------------------------------
// K0: globals precompute: g2e = globals @ Wg2.T, g2n = globals @ Wng2.T,
//     gg = globals @ Wgg.T + bg.   All [16][128].
__global__ __launch_bounds__(256) void k_glob(
    const float* __restrict__ globals_, const float* __restrict__ Wg2,
    const float* __restrict__ Wng2, const float* __restrict__ Wgg,
    const float* __restrict__ bg, float* __restrict__ g2e,
    float* __restrict__ g2n, float* __restrict__ gg) {
  int idx = blockIdx.x * 256 + threadIdx.x;
  if (idx >= 3 * 2048) return;
  int arr = idx >> 11;
  int rem = idx & 2047;
  int g = rem >> 7, c = rem & 127;
  const float* W = arr == 0 ? Wg2 : (arr == 1 ? Wng2 : Wgg);
  float acc = (arr == 2) ? bg[c] : 0.f;
#pragma unroll
  for (int k = 0; k < 16; ++k) acc += globals_[g * 16 + k] * W[c * 16 + k];
  float* o = arr == 0 ? g2e : (arr == 1 ? g2n : gg);
  o[rem] = acc;
}

// ---------------------------------------------------------------------------
// K1: counts.
__global__ __launch_bounds__(256) void k_counts(
    const int* __restrict__ recv, const int* __restrict__ node_graph,
    int* __restrict__ cnt_node, int* __restrict__ node_cnt_g,
    int* __restrict__ edge_cnt_g) {
  __shared__ int le[NG], ln[NG];
  int tid = threadIdx.x;
  if (tid < NG) { le[tid] = 0; ln[tid] = 0; }
  __syncthreads();
  int idx = blockIdx.x * 256 + tid;
  if (idx < N_EDGES) {
    int r = recv[idx];
    atomicAdd(&cnt_node[r], 1);
    atomicAdd(&le[node_graph[r]], 1);
  } else if (idx < N_EDGES + N_NODES) {
    int n = idx - N_EDGES;
    atomicAdd(&ln[node_graph[n]], 1);
  }
  __syncthreads();
  if (tid < NG && le[tid]) atomicAdd(&edge_cnt_g[tid], le[tid]);
  if (tid >= NG && tid < 2 * NG && ln[tid - NG]) atomicAdd(&node_cnt_g[tid - NG], ln[tid - NG]);
}

// ---------------------------------------------------------------------------
// K1b: exclusive prefix sum (shuffle-based, 1024 elems/iter, 3 barriers/iter).
__global__ __launch_bounds__(256) void k_scan(const int* __restrict__ cnt,
                                              int* __restrict__ offset,
                                              int* __restrict__ cursor) {
  __shared__ int wsum[4];
  __shared__ int carry_s;
  int tid = threadIdx.x, lane = tid & 63, wv = tid >> 6;
  if (tid == 0) carry_s = 0;
  __syncthreads();
  for (int base = 0; base < N_NODES; base += 1024) {
    int idx = base + tid * 4;
    int v[4];
    int s = 0;
#pragma unroll
    for (int i = 0; i < 4; ++i) {
      v[i] = (idx + i < N_NODES) ? cnt[idx + i] : 0;
      s += v[i];
    }
    int ps = s;
#pragma unroll
    for (int d = 1; d < 64; d <<= 1) {
      int t = __shfl_up(ps, d, 64);
      if (lane >= d) ps += t;
    }
    if (lane == 63) wsum[wv] = ps;
    __syncthreads();
    int wbase = carry_s;
    for (int w2 = 0; w2 < wv; ++w2) wbase += wsum[w2];
    int run = wbase + ps - s;
#pragma unroll
    for (int i = 0; i < 4; ++i) {
      if (idx + i < N_NODES) {
        offset[idx + i] = run;
        cursor[idx + i] = 0;
      }
      run += v[i];
    }
    __syncthreads();
    if (tid == 0) carry_s += wsum[0] + wsum[1] + wsum[2] + wsum[3];
    __syncthreads();
  }
  if (tid == 0) offset[N_NODES] = carry_s;
}

// ---------------------------------------------------------------------------
// K1c: scatter edges into CSR positions; record row graph-id.
__global__ __launch_bounds__(256) void k_scatter(
    const int* __restrict__ recv, const int* __restrict__ node_graph,
    const int* __restrict__ offset, int* __restrict__ cursor,
    int* __restrict__ pos2edge, int* __restrict__ rowgid_e) {
  int e = blockIdx.x * 256 + threadIdx.x;
  if (e >= N_EDGES) return;
  int n = recv[e];
  int slot = atomicAdd(&cursor[n], 1);
  int pos = offset[n] + slot;
  pos2edge[pos] = e;
  rowgid_e[pos] = node_graph[n];
}

// ---------------------------------------------------------------------------
// K1d: convert weights to bf16; concat [Wn1|Win1] -> [256][320],
//      [Wn2|Win2] -> [128][384].
__global__ __launch_bounds__(256) void k_wprep(
    const float* __restrict__ We1, const float* __restrict__ Wn1,
    const float* __restrict__ Win1, const float* __restrict__ We2,
    const float* __restrict__ Wn2, const float* __restrict__ Win2,
    bf16* __restrict__ Wb_e1, bf16* __restrict__ Wb_n1,
    bf16* __restrict__ Wb_e2, bf16* __restrict__ Wb_n2) {
  int i = blockIdx.x * 256 + threadIdx.x;
  float v;
  bf16* dst;
  int di;
  if (i < 8192) {
    v = We1[i]; dst = Wb_e1; di = i;
  } else if (i < 90112) {
    int j = i - 8192, r = j / 320, c = j % 320;
    v = c < 64 ? Wn1[r * 64 + c] : Win1[r * 256 + (c - 64)];
    dst = Wb_n1; di = j;
  } else if (i < 122880) {
    int j = i - 90112;
    v = We2[j]; dst = Wb_e2; di = j;
  } else {
    int j = i - 122880, r = j / 384, c = j % 384;
    v = c < 256 ? Wn2[r * 256 + c] : Win2[r * 128 + (c - 256)];
    dst = Wb_n2; di = j;
  }
  dst[di] = __float2bfloat16(v);
}

// ---------------------------------------------------------------------------
// K1e: gather edge_feats rows in CSR order, convert to bf16.
__global__ __launch_bounds__(256) void k_gather_ef(
    const float* __restrict__ ef, const int* __restrict__ pos2edge,
    bf16* __restrict__ out) {
  int t = blockIdx.x * 256 + threadIdx.x;
  int p = t >> 3, q = t & 7;
  int e = pos2edge[p];
  float4 v = *(const float4*)(ef + (size_t)e * 32 + q * 4);
  short4v o = {f2bs(v.x), f2bs(v.y), f2bs(v.z), f2bs(v.w)};
  *(short4v*)((short*)out + (size_t)p * 32 + q * 4) = o;
}

// ---------------------------------------------------------------------------
// K1f: node_feats -> bf16 into xn1[:, 0:64] (row stride 320).
__global__ __launch_bounds__(256) void k_cvt_nf(const float* __restrict__ nf,
                                                bf16* __restrict__ xn1) {
  int t = blockIdx.x * 256 + threadIdx.x;
  int n = t >> 4, q = t & 15;
  if (n >= N_NODES) return;
  float4 v = *(const float4*)(nf + (size_t)n * 64 + q * 4);
  short4v o = {f2bs(v.x), f2bs(v.y), f2bs(v.z), f2bs(v.w)};
  *(short4v*)((short*)xn1 + (size_t)n * 320 + q * 4) = o;
}

// ---------------------------------------------------------------------------
// Unified MFMA GEMM: out[M][outstride] (bf16, cols 0..N-1) =
//   relu(A[M][K](bf16) @ Wb[N][K].T + bias[N] (+ extra[rowgid[m]][N]))
// Block: 64 rows x N cols, 4 waves (wave w owns rows w*16..w*16+15).
// W staged per K-chunk (KC=64) in LDS with T2 XOR-swizzle (2-way max).
// Epilogue transposes through LDS for coalesced 16B stores.
template <int K, int N, bool HAS_EXTRA>
__global__ __launch_bounds__(256) void k_gemm(
    const bf16* A, const bf16* __restrict__ Wb, const float* __restrict__ bias,
    const float* __restrict__ extra, const int* __restrict__ rowgid, bf16* out,
    int outstride, int M) {
  constexpr int KC = (K < 64) ? K : 64;
  static_assert(K % KC == 0, "K must be multiple of chunk");
  constexpr int NF = N / 16;
  constexpr int WBYTES = N * 128;            // N rows x 128B (KC<=64 bf16)
  constexpr int OP = N + 8;                  // padded out-tile row (elems)
  constexpr int OBYTES = 64 * OP * 2;
  constexpr int SBYTES = WBYTES > OBYTES ? WBYTES : OBYTES;
  __shared__ __align__(16) char smem[SBYTES];
  const int tid = threadIdx.x;
  const int wave = tid >> 6, lane = tid & 63;
  const int l15 = lane & 15, grp = lane >> 4;
  const long r0 = (long)blockIdx.x * 64;
  const long arow = r0 + wave * 16 + l15;    // A-operand row for this lane
  f32x4 acc[NF] = {};
  for (int k0 = 0; k0 < K; k0 += KC) {
    constexpr int NSLOT = N * KC / 8;        // 16B slots in chunk
#pragma unroll
    for (int s = 0; s < NSLOT / 256; ++s) {
      int slot = tid + s * 256;
      int n = slot / (KC / 8);
      int cg = slot % (KC / 8);
      short8v w8 = *(const short8v*)((const short*)Wb + (size_t)n * K + k0 + cg * 8);
      int byt = n * 128 + ((cg * 16) ^ ((n & 7) << 4));
      *(short8v*)(smem + byt) = w8;
    }
    __syncthreads();
#pragma unroll
    for (int kk = 0; kk < KC; kk += 32) {
      short8v a8 = *(const short8v*)((const short*)A + (size_t)arow * K + k0 + kk + grp * 8);
#pragma unroll
      for (int n = 0; n < NF; ++n) {
        int wrow = n * 16 + l15;
        int byt = wrow * 128 + ((kk * 2 + grp * 16) ^ ((wrow & 7) << 4));
        short8v b8 = *(const short8v*)(smem + byt);
        acc[n] = __builtin_amdgcn_mfma_f32_16x16x32_bf16(a8, b8, acc[n], 0, 0, 0);
      }
    }
    __syncthreads();
  }
  // epilogue: bias (+extra) + relu -> bf16 LDS tile [64][OP]
  bf16* olds = (bf16*)smem;
  int rg[4] = {0, 0, 0, 0};
  if constexpr (HAS_EXTRA) {
#pragma unroll
    for (int i = 0; i < 4; ++i) {
      long row = r0 + wave * 16 + grp * 4 + i;
      rg[i] = rowgid[row < M ? row : 0];
    }
  }
#pragma unroll
  for (int n = 0; n < NF; ++n) {
    int col = n * 16 + l15;
    float bv = bias[col];
#pragma unroll
    for (int i = 0; i < 4; ++i) {
      float v = acc[n][i] + bv;
      if constexpr (HAS_EXTRA) v += extra[rg[i] * N + col];
      v = v > 0.f ? v : 0.f;
      olds[(wave * 16 + grp * 4 + i) * OP + col] = __float2bfloat16(v);
    }
  }
  __syncthreads();
  // flush LDS -> global, coalesced 16B stores
  constexpr int NCG = N / 8;
#pragma unroll
  for (int s = 0; s < 64 * NCG / 256; ++s) {
    int slot = tid + s * 256;
    int rl = slot / NCG, cg = slot % NCG;
    long row = r0 + rl;
    if (row < M)
      *(short8v*)((short*)out + (size_t)row * outstride + cg * 8) =
          *(const short8v*)((const short*)olds + (size_t)rl * OP + cg * 8);
  }
}

// ---------------------------------------------------------------------------
// K2b: agg1 mean (pre-divided, bf16) into xn1[:, 64:320].
__global__ __launch_bounds__(256) void k_agg1(const bf16* __restrict__ e1s,
                                              const int* __restrict__ offset,
                                              bf16* __restrict__ xn1) {
  int n = blockIdx.x, c = threadIdx.x;
  int s = offset[n], t = offset[n + 1];
  float acc = 0.f;
  for (int p = s; p < t; ++p) acc += __bfloat162float(e1s[(size_t)p * 256 + c]);
  float inv = 1.f / (float)((t - s) > 1 ? (t - s) : 1);
  xn1[(size_t)n * 320 + 64 + c] = __float2bfloat16(acc * inv);
}

// ---------------------------------------------------------------------------
// K4b: agg2 sum (f32 for gsum) + mean (bf16) into xn2[:, 256:384].
//      e2 lives in cols 0..127 of e1s rows (in-place).
__global__ __launch_bounds__(128) void k_agg2(const bf16* __restrict__ e2s,
                                              const int* __restrict__ offset,
                                              float* __restrict__ agg2f,
                                              bf16* __restrict__ xn2) {
  int n = blockIdx.x, c = threadIdx.x;
  int s = offset[n], t = offset[n + 1];
  float acc = 0.f;
  for (int p = s; p < t; ++p) acc += __bfloat162float(e2s[(size_t)p * 256 + c]);
  agg2f[(size_t)n * 128 + c] = acc;
  float inv = 1.f / (float)((t - s) > 1 ? (t - s) : 1);
  xn2[(size_t)n * 384 + 256 + c] = __float2bfloat16(acc * inv);
}

// ---------------------------------------------------------------------------
// K6: per-graph sums of n2 and agg2f (edge_sum[g] = sum_{n in g} agg2f[n]).
__global__ __launch_bounds__(128) void k_gsum(
    const bf16* __restrict__ n2, const float* __restrict__ agg2f,
    const int* __restrict__ node_graph, float* __restrict__ node_sum,
    float* __restrict__ edge_sum) {
  const int c = threadIdx.x;
  const int n0 = blockIdx.x * 100;
  float na = 0.f, ea = 0.f;
  int gcur = node_graph[n0];
  for (int j = 0; j < 100; ++j) {
    int n = n0 + j;
    int g = node_graph[n];
    if (g != gcur) {
      atomicAdd(&node_sum[gcur * 128 + c], na);
      atomicAdd(&edge_sum[gcur * 128 + c], ea);
      na = 0.f;
      ea = 0.f;
      gcur = g;
    }
    na += __bfloat162float(n2[(size_t)n * 128 + c]);
    ea += agg2f[(size_t)n * 128 + c];
  }
  atomicAdd(&node_sum[gcur * 128 + c], na);
  atomicAdd(&edge_sum[gcur * 128 + c], ea);
}

// ---------------------------------------------------------------------------
// K7: out = node_avg @ Wgn.T + edge_avg @ Wge.T + gg   [16,128]
__global__ __launch_bounds__(128) void k_final(
    const float* __restrict__ node_sum, const float* __restrict__ edge_sum,
    const int* __restrict__ node_cnt_g, const int* __restrict__ edge_cnt_g,
    const float* __restrict__ Wgn, const float* __restrict__ Wge,
    const float* __restrict__ gg, float* __restrict__ out) {
  __shared__ float navg[128], eavg[128];
  const int g = blockIdx.x, c = threadIdx.x;
  int nc = node_cnt_g[g];
  nc = nc > 1 ? nc : 1;
  int ec = edge_cnt_g[g];
  ec = ec > 1 ? ec : 1;
  navg[c] = node_sum[g * 128 + c] / (float)nc;
  eavg[c] = edge_sum[g * 128 + c] / (float)ec;
  __syncthreads();
  float acc = gg[g * 128 + c];
#pragma unroll 4
  for (int k = 0; k < 128; ++k)
    acc += navg[k] * Wgn[c * 128 + k] + eavg[k] * Wge[c * 128 + k];
  out[g * 128 + c] = acc;
}

// ---------------------------------------------------------------------------
extern "C" void kernel_launch(void* const* d_in, const int* in_sizes, int n_in,
                              void* d_out, int out_size, void* d_ws, size_t ws_size,
                              hipStream_t stream) {
  const float* node_feats = (const float*)d_in[0];
  const float* edge_feats = (const float*)d_in[1];
  const float* globals_ = (const float*)d_in[2];
  const float* We1 = (const float*)d_in[3];
  const float* be1 = (const float*)d_in[4];
  const float* Wn1 = (const float*)d_in[5];
  const float* Win1 = (const float*)d_in[6];
  const float* bn1 = (const float*)d_in[7];
  const float* We2 = (const float*)d_in[8];
  const float* Wg2 = (const float*)d_in[9];
  const float* be2 = (const float*)d_in[10];
  const float* Wn2 = (const float*)d_in[11];
  const float* Win2 = (const float*)d_in[12];
  const float* Wng2 = (const float*)d_in[13];
  const float* bn2 = (const float*)d_in[14];
  const float* Wgn = (const float*)d_in[15];
  const float* Wge = (const float*)d_in[16];
  const float* Wgg = (const float*)d_in[17];
  const float* bg = (const float*)d_in[18];
  const int* receivers = (const int*)d_in[19];
  const int* node_graph = (const int*)d_in[20];
  float* out = (float*)d_out;

  char* ws = (char*)d_ws;
  size_t off = 0;
  auto alloc = [&](size_t bytes) {
    size_t o = off;
    off += (bytes + 255) & ~(size_t)255;
    return o;
  };
  const int NP = 20032;  // N_NODES padded to 64
  // --- zero region ---
  int* cnt_node = (int*)(ws + alloc((size_t)N_NODES * 4));
  int* node_cnt_g = (int*)(ws + alloc(NG * 4));
  int* edge_cnt_g = (int*)(ws + alloc(NG * 4));
  float* node_sum = (float*)(ws + alloc(NG * 128 * 4));
  float* edge_sum = (float*)(ws + alloc(NG * 128 * 4));
  size_t zero_bytes = off;
  // --- rewritten every call ---
  int* offset = (int*)(ws + alloc((size_t)(N_NODES + 1) * 4));
  int* cursor = (int*)(ws + alloc((size_t)N_NODES * 4));
  int* pos2edge = (int*)(ws + alloc((size_t)N_EDGES * 4));
  int* rowgid_e = (int*)(ws + alloc((size_t)N_EDGES * 4));
  float* g2e = (float*)(ws + alloc(NG * 128 * 4));
  float* g2n = (float*)(ws + alloc(NG * 128 * 4));
  float* gg = (float*)(ws + alloc(NG * 128 * 4));
  bf16* Wb_e1 = (bf16*)(ws + alloc(8192 * 2));
  bf16* Wb_n1 = (bf16*)(ws + alloc(81920 * 2));
  bf16* Wb_e2 = (bf16*)(ws + alloc(32768 * 2));
  bf16* Wb_n2 = (bf16*)(ws + alloc(49152 * 2));
  bf16* xn1 = (bf16*)(ws + alloc((size_t)NP * 320 * 2));
  bf16* e1s = (bf16*)(ws + alloc((size_t)N_EDGES * 256 * 2));
  // union: ef_s (dead after k_e1) overlaps {xn2, agg2f, n2buf}
  size_t uoff = off;
  bf16* ef_s = (bf16*)(ws + uoff);                      // E*32*2 = 20.48 MB
  bf16* xn2 = (bf16*)(ws + uoff);                       // NP*384*2 = 15.39 MB
  float* agg2f = (float*)(ws + uoff + (size_t)NP * 384 * 2);
  bf16* n2buf = (bf16*)(ws + uoff + (size_t)NP * 384 * 2 + (size_t)N_NODES * 128 * 4);
  (void)ws_size;

  hipMemsetAsync(d_ws, 0, zero_bytes, stream);
  k_glob<<<24, 256, 0, stream>>>(globals_, Wg2, Wng2, Wgg, bg, g2e, g2n, gg);
  k_counts<<<(N_EDGES + N_NODES + 255) / 256, 256, 0, stream>>>(
      receivers, node_graph, cnt_node, node_cnt_g, edge_cnt_g);
  k_scan<<<1, 256, 0, stream>>>(cnt_node, offset, cursor);
  k_scatter<<<(N_EDGES + 255) / 256, 256, 0, stream>>>(
      receivers, node_graph, offset, cursor, pos2edge, rowgid_e);
  k_wprep<<<672, 256, 0, stream>>>(We1, Wn1, Win1, We2, Wn2, Win2, Wb_e1,
                                   Wb_n1, Wb_e2, Wb_n2);
  k_gather_ef<<<N_EDGES * 8 / 256, 256, 0, stream>>>(edge_feats, pos2edge, ef_s);
  k_cvt_nf<<<N_NODES * 16 / 256, 256, 0, stream>>>(node_feats, xn1);
  // e1 = relu(ef @ We1.T + be1)  [E,256]
  k_gemm<32, 256, false><<<N_EDGES / 64, 256, 0, stream>>>(
      ef_s, Wb_e1, be1, nullptr, nullptr, e1s, 256, N_EDGES);
  k_agg1<<<N_NODES, 256, 0, stream>>>(e1s, offset, xn1);
  // n1 = relu([nf|agg1] @ [Wn1|Win1].T + bn1) -> xn2[:,0:256]
  k_gemm<320, 256, false><<<NP / 64, 256, 0, stream>>>(
      xn1, Wb_n1, bn1, nullptr, nullptr, xn2, 384, N_NODES);
  // e2 = relu(e1 @ We2.T + g2e[g] + be2) -> in-place e1s cols 0..127
  k_gemm<256, 128, true><<<N_EDGES / 64, 256, 0, stream>>>(
      e1s, Wb_e2, be2, g2e, rowgid_e, e1s, 256, N_EDGES);
  k_agg2<<<N_NODES, 128, 0, stream>>>(e1s, offset, agg2f, xn2);
  // n2 = relu([n1|agg2] @ [Wn2|Win2].T + g2n[g] + bn2) [N,128]
  k_gemm<384, 128, true><<<NP / 64, 256, 0, stream>>>(
      xn2, Wb_n2, bn2, g2n, node_graph, n2buf, 128, N_NODES);
  k_gsum<<<N_NODES / 100, 128, 0, stream>>>(n2buf, agg2f, node_graph, node_sum,
                                            edge_sum);
  k_final<<<NG, 128, 0, stream>>>(node_sum, edge_sum, node_cnt_g, edge_cnt_g,
                                  Wgn, Wge, gg, out);
}

// Round 4
// 292.658 us; speedup vs baseline: 6.2283x; 1.1773x over previous
//
#include <hip/hip_runtime.h>
#include <hip/hip_bf16.h>

#define N_NODES 20000
#define N_EDGES 320000
#define NG 16

using bf16 = __hip_bfloat16;
typedef __attribute__((ext_vector_type(8))) short short8v;
typedef __attribute__((ext_vector_type(4))) short short4v;
typedef __attribute__((ext_vector_type(4))) float f32x4;

static __device__ __forceinline__ short f2bs(float f) {
  bf16 h = __float2bfloat16(f);
  union { bf16 b; short s; } u;
  u.b = h;
  return u.s;
}
static __device__ __forceinline__ float bs2f(short s) {
  union { short s; bf16 b; } u;
  u.s = s;
  return __bfloat162float(u.b);
}

// ---------------------------------------------------------------------------
// K0: globals precompute: g2e = globals @ Wg2.T, g2n = globals @ Wng2.T,
//     gg = globals @ Wgg.T + bg.   All [16][128].
__global__ __launch_bounds__(256) void k_glob(
    const float* __restrict__ globals_, const float* __restrict__ Wg2,
    const float* __restrict__ Wng2, const float* __restrict__ Wgg,
    const float* __restrict__ bg, float* __restrict__ g2e,
    float* __restrict__ g2n, float* __restrict__ gg) {
  int idx = blockIdx.x * 256 + threadIdx.x;
  if (idx >= 3 * 2048) return;
  int arr = idx >> 11;
  int rem = idx & 2047;
  int g = rem >> 7, c = rem & 127;
  const float* W = arr == 0 ? Wg2 : (arr == 1 ? Wng2 : Wgg);
  float acc = (arr == 2) ? bg[c] : 0.f;
#pragma unroll
  for (int k = 0; k < 16; ++k) acc += globals_[g * 16 + k] * W[c * 16 + k];
  float* o = arr == 0 ? g2e : (arr == 1 ? g2n : gg);
  o[rem] = acc;
}

// ---------------------------------------------------------------------------
// K1: counts.
__global__ __launch_bounds__(256) void k_counts(
    const int* __restrict__ recv, const int* __restrict__ node_graph,
    int* __restrict__ cnt_node, int* __restrict__ node_cnt_g,
    int* __restrict__ edge_cnt_g) {
  __shared__ int le[NG], ln[NG];
  int tid = threadIdx.x;
  if (tid < NG) { le[tid] = 0; ln[tid] = 0; }
  __syncthreads();
  int idx = blockIdx.x * 256 + tid;
  if (idx < N_EDGES) {
    int r = recv[idx];
    atomicAdd(&cnt_node[r], 1);
    atomicAdd(&le[node_graph[r]], 1);
  } else if (idx < N_EDGES + N_NODES) {
    int n = idx - N_EDGES;
    atomicAdd(&ln[node_graph[n]], 1);
  }
  __syncthreads();
  if (tid < NG && le[tid]) atomicAdd(&edge_cnt_g[tid], le[tid]);
  if (tid >= NG && tid < 2 * NG && ln[tid - NG]) atomicAdd(&node_cnt_g[tid - NG], ln[tid - NG]);
}

// ---------------------------------------------------------------------------
// K1b: exclusive prefix sum (shuffle-based).
__global__ __launch_bounds__(256) void k_scan(const int* __restrict__ cnt,
                                              int* __restrict__ offset,
                                              int* __restrict__ cursor) {
  __shared__ int wsum[4];
  __shared__ int carry_s;
  int tid = threadIdx.x, lane = tid & 63, wv = tid >> 6;
  if (tid == 0) carry_s = 0;
  __syncthreads();
  for (int base = 0; base < N_NODES; base += 1024) {
    int idx = base + tid * 4;
    int v[4];
    int s = 0;
#pragma unroll
    for (int i = 0; i < 4; ++i) {
      v[i] = (idx + i < N_NODES) ? cnt[idx + i] : 0;
      s += v[i];
    }
    int ps = s;
#pragma unroll
    for (int d = 1; d < 64; d <<= 1) {
      int t = __shfl_up(ps, d, 64);
      if (lane >= d) ps += t;
    }
    if (lane == 63) wsum[wv] = ps;
    __syncthreads();
    int wbase = carry_s;
    for (int w2 = 0; w2 < wv; ++w2) wbase += wsum[w2];
    int run = wbase + ps - s;
#pragma unroll
    for (int i = 0; i < 4; ++i) {
      if (idx + i < N_NODES) {
        offset[idx + i] = run;
        cursor[idx + i] = 0;
      }
      run += v[i];
    }
    __syncthreads();
    if (tid == 0) carry_s += wsum[0] + wsum[1] + wsum[2] + wsum[3];
    __syncthreads();
  }
  if (tid == 0) offset[N_NODES] = carry_s;
}

// ---------------------------------------------------------------------------
// K1c: scatter edges into CSR positions.
__global__ __launch_bounds__(256) void k_scatter(
    const int* __restrict__ recv, const int* __restrict__ offset,
    int* __restrict__ cursor, int* __restrict__ pos2edge,
    int* __restrict__ pos2node) {
  int e = blockIdx.x * 256 + threadIdx.x;
  if (e >= N_EDGES) return;
  int n = recv[e];
  int slot = atomicAdd(&cursor[n], 1);
  int pos = offset[n] + slot;
  pos2edge[pos] = e;
  pos2node[pos] = n;
}

// ---------------------------------------------------------------------------
// K1d: convert weights to bf16; concat [Wn1|Win1] -> [256][320],
//      [Wn2|Win2] -> [128][384].
__global__ __launch_bounds__(256) void k_wprep(
    const float* __restrict__ We1, const float* __restrict__ Wn1,
    const float* __restrict__ Win1, const float* __restrict__ We2,
    const float* __restrict__ Wn2, const float* __restrict__ Win2,
    bf16* __restrict__ Wb_e1, bf16* __restrict__ Wb_n1,
    bf16* __restrict__ Wb_e2, bf16* __restrict__ Wb_n2) {
  int i = blockIdx.x * 256 + threadIdx.x;
  float v;
  bf16* dst;
  int di;
  if (i < 8192) {
    v = We1[i]; dst = Wb_e1; di = i;
  } else if (i < 90112) {
    int j = i - 8192, r = j / 320, c = j % 320;
    v = c < 64 ? Wn1[r * 64 + c] : Win1[r * 256 + (c - 64)];
    dst = Wb_n1; di = j;
  } else if (i < 122880) {
    int j = i - 90112;
    v = We2[j]; dst = Wb_e2; di = j;
  } else {
    int j = i - 122880, r = j / 384, c = j % 384;
    v = c < 256 ? Wn2[r * 256 + c] : Win2[r * 128 + (c - 256)];
    dst = Wb_n2; di = j;
  }
  dst[di] = __float2bfloat16(v);
}

// ---------------------------------------------------------------------------
// K1f: node_feats -> bf16 into xn1[:, 0:64] (row stride 320).
__global__ __launch_bounds__(256) void k_cvt_nf(const float* __restrict__ nf,
                                                bf16* __restrict__ xn1) {
  int t = blockIdx.x * 256 + threadIdx.x;
  int n = t >> 4, q = t & 15;
  if (n >= N_NODES) return;
  float4 v = *(const float4*)(nf + (size_t)n * 64 + q * 4);
  short4v o = {f2bs(v.x), f2bs(v.y), f2bs(v.z), f2bs(v.w)};
  *(short4v*)((short*)xn1 + (size_t)n * 320 + q * 4) = o;
}

// ---------------------------------------------------------------------------
// FUSED edge pipeline: per 64-CSR-row block:
//   e1 = relu(ef[pos2edge] @ We1.T + be1)         (MFMA K=32, N=256, regs)
//   -> LDS tile (bf16) -> segmented col-sum -> atomicAdd agg1f
//   e2 = relu(e1 @ We2.T + g2e[gid] + be2)        (MFMA K=256, N=128, A from LDS)
//   -> LDS tile (f32)  -> segmented col-sum -> atomicAdd agg2f
// e1/e2 never hit global memory.
__global__ __launch_bounds__(256) void k_edge(
    const float* __restrict__ edge_feats, const bf16* __restrict__ We1b,
    const bf16* __restrict__ We2b, const float* __restrict__ be1,
    const float* __restrict__ be2, const float* __restrict__ g2e,
    const int* __restrict__ pos2edge, const int* __restrict__ pos2node,
    const int* __restrict__ node_graph, float* __restrict__ agg1f,
    float* __restrict__ agg2f) {
  __shared__ __align__(16) char wlds[32768];   // swizzled W staging
  __shared__ __align__(16) char tlds[33792];   // e1 bf16 [64][264] / e2 f32 [64][132]
  __shared__ int rownode_s[64];
  __shared__ int rowgid_s[64];
  const int tid = threadIdx.x;
  const int wave = tid >> 6, lane = tid & 63;
  const int l15 = lane & 15, grp = lane >> 4;
  const int p0 = blockIdx.x * 64;

  if (tid < 64) {
    int rn = pos2node[p0 + tid];
    rownode_s[tid] = rn;
    rowgid_s[tid] = node_graph[rn];
  }
  // stage We1b [256 out][32 k] -> row stride 128B, XOR-swizzled 16B slots
#pragma unroll
  for (int s = 0; s < 4; ++s) {
    int slot = tid + s * 256;
    int n = slot >> 2, cg = slot & 3;
    short8v w8 = *(const short8v*)((const short*)We1b + n * 32 + cg * 8);
    *(short8v*)(wlds + n * 128 + ((cg * 16) ^ ((n & 7) << 4))) = w8;
  }
  // A1 frag: row = p0 + wave*16 + l15, k = grp*8..+8 (f32 -> bf16)
  int e = pos2edge[p0 + wave * 16 + l15];
  const float* efrow = edge_feats + (size_t)e * 32 + grp * 8;
  float4 af0 = *(const float4*)(efrow);
  float4 af1 = *(const float4*)(efrow + 4);
  short8v a1;
  a1[0] = f2bs(af0.x); a1[1] = f2bs(af0.y); a1[2] = f2bs(af0.z); a1[3] = f2bs(af0.w);
  a1[4] = f2bs(af1.x); a1[5] = f2bs(af1.y); a1[6] = f2bs(af1.z); a1[7] = f2bs(af1.w);
  __syncthreads();
  // e1 MFMA: 16 col-frags
  f32x4 acc1[16] = {};
#pragma unroll
  for (int nf = 0; nf < 16; ++nf) {
    int n = nf * 16 + l15;
    short8v b8 = *(const short8v*)(wlds + n * 128 + ((grp * 16) ^ ((n & 7) << 4)));
    acc1[nf] = __builtin_amdgcn_mfma_f32_16x16x32_bf16(a1, b8, acc1[nf], 0, 0, 0);
  }
  // e1 epilogue -> tlds bf16 [64][264]
  short* t16 = (short*)tlds;
#pragma unroll
  for (int nf = 0; nf < 16; ++nf) {
    int col = nf * 16 + l15;
    float bv = be1[col];
#pragma unroll
    for (int i = 0; i < 4; ++i) {
      float v = acc1[nf][i] + bv;
      v = v > 0.f ? v : 0.f;
      t16[(wave * 16 + grp * 4 + i) * 264 + col] = f2bs(v);
    }
  }
  __syncthreads();
  // segment-boundary mask (wave-uniform; rows sorted by node)
  unsigned long long fmask = 1ull << 63;
#pragma unroll
  for (int r = 0; r < 63; ++r)
    if (rownode_s[r + 1] != rownode_s[r]) fmask |= 1ull << r;
  // A2 frags: full K=256 e1 row from tlds
  short8v a2[8];
#pragma unroll
  for (int j = 0; j < 8; ++j)
    a2[j] = *(const short8v*)(tlds + (wave * 16 + l15) * 528 + (j * 32 + grp * 8) * 2);
  // agg1 segmented col-sum (thread t = col t)
  {
    float run = 0.f;
#pragma unroll
    for (int r = 0; r < 64; ++r) {
      run += bs2f(t16[r * 264 + tid]);
      if ((fmask >> r) & 1) {
        atomicAdd(&agg1f[(size_t)rownode_s[r] * 256 + tid], run);
        run = 0.f;
      }
    }
  }
  // e2 MFMA: K=256 in 4 chunks of 64 (We2 staged per chunk)
  f32x4 acc2[8] = {};
  for (int c = 0; c < 4; ++c) {
    __syncthreads();
#pragma unroll
    for (int s = 0; s < 4; ++s) {
      int slot = tid + s * 256;
      int n = slot >> 3, cg = slot & 7;
      short8v w8 = *(const short8v*)((const short*)We2b + n * 256 + c * 64 + cg * 8);
      *(short8v*)(wlds + n * 128 + ((cg * 16) ^ ((n & 7) << 4))) = w8;
    }
    __syncthreads();
#pragma unroll
    for (int kki = 0; kki < 2; ++kki) {
      short8v a8 = a2[c * 2 + kki];
#pragma unroll
      for (int nf = 0; nf < 8; ++nf) {
        int n = nf * 16 + l15;
        short8v b8 = *(const short8v*)(wlds + n * 128 + ((kki * 64 + grp * 16) ^ ((n & 7) << 4)));
        acc2[nf] = __builtin_amdgcn_mfma_f32_16x16x32_bf16(a8, b8, acc2[nf], 0, 0, 0);
      }
    }
  }
  // e2 epilogue -> tlds f32 [64][132] (safe: all tlds readers done before
  // any wave passed the c=0 stage barrier)
  float* tf32 = (float*)tlds;
#pragma unroll
  for (int nf = 0; nf < 8; ++nf) {
    int col = nf * 16 + l15;
    float bv = be2[col];
#pragma unroll
    for (int i = 0; i < 4; ++i) {
      int row = wave * 16 + grp * 4 + i;
      float v = acc2[nf][i] + bv + g2e[rowgid_s[row] * 128 + col];
      v = v > 0.f ? v : 0.f;
      tf32[row * 132 + col] = v;
    }
  }
  __syncthreads();
  // agg2 segmented col-sum (threads 0..127)
  if (tid < 128) {
    float run = 0.f;
#pragma unroll
    for (int r = 0; r < 64; ++r) {
      run += tf32[r * 132 + tid];
      if ((fmask >> r) & 1) {
        atomicAdd(&agg2f[(size_t)rownode_s[r] * 128 + tid], run);
        run = 0.f;
      }
    }
  }
}

// ---------------------------------------------------------------------------
// K_fin: divide agg sums by degree, emit bf16 into xn1[:,64:320], xn2[:,256:384].
__global__ __launch_bounds__(384) void k_fin(
    const float* __restrict__ agg1f, const float* __restrict__ agg2f,
    const int* __restrict__ offset, bf16* __restrict__ xn1,
    bf16* __restrict__ xn2) {
  int n = blockIdx.x;
  int deg = offset[n + 1] - offset[n];
  float inv = 1.f / (float)(deg > 1 ? deg : 1);
  int t = threadIdx.x;
  if (t < 256) {
    xn1[(size_t)n * 320 + 64 + t] = __float2bfloat16(agg1f[(size_t)n * 256 + t] * inv);
  } else {
    int c = t - 256;
    xn2[(size_t)n * 384 + 256 + c] = __float2bfloat16(agg2f[(size_t)n * 128 + c] * inv);
  }
}

// ---------------------------------------------------------------------------
// Unified MFMA GEMM (node layers): out = relu(A @ Wb.T + bias (+ extra[gid])).
template <int K, int N, bool HAS_EXTRA>
__global__ __launch_bounds__(256) void k_gemm(
    const bf16* A, const bf16* __restrict__ Wb, const float* __restrict__ bias,
    const float* __restrict__ extra, const int* __restrict__ rowgid, bf16* out,
    int outstride, int M) {
  constexpr int KC = (K < 64) ? K : 64;
  static_assert(K % KC == 0, "K must be multiple of chunk");
  constexpr int NF = N / 16;
  constexpr int WBYTES = N * 128;
  constexpr int OP = N + 8;
  constexpr int OBYTES = 64 * OP * 2;
  constexpr int SBYTES = WBYTES > OBYTES ? WBYTES : OBYTES;
  __shared__ __align__(16) char smem[SBYTES];
  const int tid = threadIdx.x;
  const int wave = tid >> 6, lane = tid & 63;
  const int l15 = lane & 15, grp = lane >> 4;
  const long r0 = (long)blockIdx.x * 64;
  const long arow = r0 + wave * 16 + l15;
  f32x4 acc[NF] = {};
  for (int k0 = 0; k0 < K; k0 += KC) {
    constexpr int NSLOT = N * KC / 8;
#pragma unroll
    for (int s = 0; s < NSLOT / 256; ++s) {
      int slot = tid + s * 256;
      int n = slot / (KC / 8);
      int cg = slot % (KC / 8);
      short8v w8 = *(const short8v*)((const short*)Wb + (size_t)n * K + k0 + cg * 8);
      int byt = n * 128 + ((cg * 16) ^ ((n & 7) << 4));
      *(short8v*)(smem + byt) = w8;
    }
    __syncthreads();
#pragma unroll
    for (int kk = 0; kk < KC; kk += 32) {
      short8v a8 = *(const short8v*)((const short*)A + (size_t)arow * K + k0 + kk + grp * 8);
#pragma unroll
      for (int n = 0; n < NF; ++n) {
        int wrow = n * 16 + l15;
        int byt = wrow * 128 + ((kk * 2 + grp * 16) ^ ((wrow & 7) << 4));
        short8v b8 = *(const short8v*)(smem + byt);
        acc[n] = __builtin_amdgcn_mfma_f32_16x16x32_bf16(a8, b8, acc[n], 0, 0, 0);
      }
    }
    __syncthreads();
  }
  bf16* olds = (bf16*)smem;
  int rg[4] = {0, 0, 0, 0};
  if constexpr (HAS_EXTRA) {
#pragma unroll
    for (int i = 0; i < 4; ++i) {
      long row = r0 + wave * 16 + grp * 4 + i;
      rg[i] = rowgid[row < M ? row : 0];
    }
  }
#pragma unroll
  for (int n = 0; n < NF; ++n) {
    int col = n * 16 + l15;
    float bv = bias[col];
#pragma unroll
    for (int i = 0; i < 4; ++i) {
      float v = acc[n][i] + bv;
      if constexpr (HAS_EXTRA) v += extra[rg[i] * N + col];
      v = v > 0.f ? v : 0.f;
      olds[(wave * 16 + grp * 4 + i) * OP + col] = __float2bfloat16(v);
    }
  }
  __syncthreads();
  constexpr int NCG = N / 8;
#pragma unroll
  for (int s = 0; s < 64 * NCG / 256; ++s) {
    int slot = tid + s * 256;
    int rl = slot / NCG, cg = slot % NCG;
    long row = r0 + rl;
    if (row < M)
      *(short8v*)((short*)out + (size_t)row * outstride + cg * 8) =
          *(const short8v*)((const short*)olds + (size_t)rl * OP + cg * 8);
  }
}

// ---------------------------------------------------------------------------
// K6: per-graph sums of n2 and agg2f (edge_sum[g] = sum_{n in g} agg2f[n]).
__global__ __launch_bounds__(128) void k_gsum(
    const bf16* __restrict__ n2, const float* __restrict__ agg2f,
    const int* __restrict__ node_graph, float* __restrict__ node_sum,
    float* __restrict__ edge_sum) {
  const int c = threadIdx.x;
  const int n0 = blockIdx.x * 100;
  float na = 0.f, ea = 0.f;
  int gcur = node_graph[n0];
  for (int j = 0; j < 100; ++j) {
    int n = n0 + j;
    int g = node_graph[n];
    if (g != gcur) {
      atomicAdd(&node_sum[gcur * 128 + c], na);
      atomicAdd(&edge_sum[gcur * 128 + c], ea);
      na = 0.f;
      ea = 0.f;
      gcur = g;
    }
    na += __bfloat162float(n2[(size_t)n * 128 + c]);
    ea += agg2f[(size_t)n * 128 + c];
  }
  atomicAdd(&node_sum[gcur * 128 + c], na);
  atomicAdd(&edge_sum[gcur * 128 + c], ea);
}

// ---------------------------------------------------------------------------
// K7: out = node_avg @ Wgn.T + edge_avg @ Wge.T + gg   [16,128]
__global__ __launch_bounds__(128) void k_final(
    const float* __restrict__ node_sum, const float* __restrict__ edge_sum,
    const int* __restrict__ node_cnt_g, const int* __restrict__ edge_cnt_g,
    const float* __restrict__ Wgn, const float* __restrict__ Wge,
    const float* __restrict__ gg, float* __restrict__ out) {
  __shared__ float navg[128], eavg[128];
  const int g = blockIdx.x, c = threadIdx.x;
  int nc = node_cnt_g[g];
  nc = nc > 1 ? nc : 1;
  int ec = edge_cnt_g[g];
  ec = ec > 1 ? ec : 1;
  navg[c] = node_sum[g * 128 + c] / (float)nc;
  eavg[c] = edge_sum[g * 128 + c] / (float)ec;
  __syncthreads();
  float acc = gg[g * 128 + c];
#pragma unroll 4
  for (int k = 0; k < 128; ++k)
    acc += navg[k] * Wgn[c * 128 + k] + eavg[k] * Wge[c * 128 + k];
  out[g * 128 + c] = acc;
}

// ---------------------------------------------------------------------------
extern "C" void kernel_launch(void* const* d_in, const int* in_sizes, int n_in,
                              void* d_out, int out_size, void* d_ws, size_t ws_size,
                              hipStream_t stream) {
  const float* node_feats = (const float*)d_in[0];
  const float* edge_feats = (const float*)d_in[1];
  const float* globals_ = (const float*)d_in[2];
  const float* We1 = (const float*)d_in[3];
  const float* be1 = (const float*)d_in[4];
  const float* Wn1 = (const float*)d_in[5];
  const float* Win1 = (const float*)d_in[6];
  const float* bn1 = (const float*)d_in[7];
  const float* We2 = (const float*)d_in[8];
  const float* Wg2 = (const float*)d_in[9];
  const float* be2 = (const float*)d_in[10];
  const float* Wn2 = (const float*)d_in[11];
  const float* Win2 = (const float*)d_in[12];
  const float* Wng2 = (const float*)d_in[13];
  const float* bn2 = (const float*)d_in[14];
  const float* Wgn = (const float*)d_in[15];
  const float* Wge = (const float*)d_in[16];
  const float* Wgg = (const float*)d_in[17];
  const float* bg = (const float*)d_in[18];
  const int* receivers = (const int*)d_in[19];
  const int* node_graph = (const int*)d_in[20];
  float* out = (float*)d_out;

  char* ws = (char*)d_ws;
  size_t off = 0;
  auto alloc = [&](size_t bytes) {
    size_t o = off;
    off += (bytes + 255) & ~(size_t)255;
    return o;
  };
  const int NP = 20032;  // N_NODES padded to 64
  // --- zero region (accumulators) ---
  int* cnt_node = (int*)(ws + alloc((size_t)N_NODES * 4));
  int* node_cnt_g = (int*)(ws + alloc(NG * 4));
  int* edge_cnt_g = (int*)(ws + alloc(NG * 4));
  float* node_sum = (float*)(ws + alloc(NG * 128 * 4));
  float* edge_sum = (float*)(ws + alloc(NG * 128 * 4));
  float* agg1f = (float*)(ws + alloc((size_t)N_NODES * 256 * 4));
  float* agg2f = (float*)(ws + alloc((size_t)N_NODES * 128 * 4));
  size_t zero_bytes = off;
  // --- rewritten every call ---
  int* offset = (int*)(ws + alloc((size_t)(N_NODES + 1) * 4));
  int* cursor = (int*)(ws + alloc((size_t)N_NODES * 4));
  int* pos2edge = (int*)(ws + alloc((size_t)N_EDGES * 4));
  int* pos2node = (int*)(ws + alloc((size_t)N_EDGES * 4));
  float* g2e = (float*)(ws + alloc(NG * 128 * 4));
  float* g2n = (float*)(ws + alloc(NG * 128 * 4));
  float* gg = (float*)(ws + alloc(NG * 128 * 4));
  bf16* Wb_e1 = (bf16*)(ws + alloc(8192 * 2));
  bf16* Wb_n1 = (bf16*)(ws + alloc(81920 * 2));
  bf16* Wb_e2 = (bf16*)(ws + alloc(32768 * 2));
  bf16* Wb_n2 = (bf16*)(ws + alloc(49152 * 2));
  bf16* xn1 = (bf16*)(ws + alloc((size_t)NP * 320 * 2));
  bf16* xn2 = (bf16*)(ws + alloc((size_t)NP * 384 * 2));
  bf16* n2buf = (bf16*)(ws + alloc((size_t)N_NODES * 128 * 2));
  (void)ws_size;

  hipMemsetAsync(d_ws, 0, zero_bytes, stream);
  k_glob<<<24, 256, 0, stream>>>(globals_, Wg2, Wng2, Wgg, bg, g2e, g2n, gg);
  k_counts<<<(N_EDGES + N_NODES + 255) / 256, 256, 0, stream>>>(
      receivers, node_graph, cnt_node, node_cnt_g, edge_cnt_g);
  k_scan<<<1, 256, 0, stream>>>(cnt_node, offset, cursor);
  k_scatter<<<(N_EDGES + 255) / 256, 256, 0, stream>>>(receivers, offset,
                                                       cursor, pos2edge,
                                                       pos2node);
  k_wprep<<<672, 256, 0, stream>>>(We1, Wn1, Win1, We2, Wn2, Win2, Wb_e1,
                                   Wb_n1, Wb_e2, Wb_n2);
  k_cvt_nf<<<N_NODES * 16 / 256, 256, 0, stream>>>(node_feats, xn1);
  k_edge<<<N_EDGES / 64, 256, 0, stream>>>(edge_feats, Wb_e1, Wb_e2, be1, be2,
                                           g2e, pos2edge, pos2node, node_graph,
                                           agg1f, agg2f);
  k_fin<<<N_NODES, 384, 0, stream>>>(agg1f, agg2f, offset, xn1, xn2);
  // n1 = relu([nf|agg1] @ [Wn1|Win1].T + bn1) -> xn2[:,0:256]
  k_gemm<320, 256, false><<<NP / 64, 256, 0, stream>>>(
      xn1, Wb_n1, bn1, nullptr, nullptr, xn2, 384, N_NODES);
  // n2 = relu([n1|agg2] @ [Wn2|Win2].T + g2n[g] + bn2) [N,128]
  k_gemm<384, 128, true><<<NP / 64, 256, 0, stream>>>(
      xn2, Wb_n2, bn2, g2n, node_graph, n2buf, 128, N_NODES);
  k_gsum<<<N_NODES / 100, 128, 0, stream>>>(n2buf, agg2f, node_graph, node_sum,
                                            edge_sum);
  k_final<<<NG, 128, 0, stream>>>(node_sum, edge_sum, node_cnt_g, edge_cnt_g,
                                  Wgn, Wge, gg, out);
}